// Round 23
// baseline (341.300 us; speedup 1.0000x reference)
//
#include <hip/hip_runtime.h>
#include <hip/hip_bf16.h>

#define NH 96
#define NW 96
#define NB 8
#define CIN 192
#define COUT 768   // 4 heads * 3 * 64
#define PH 98      // padded spatial dim

typedef __attribute__((ext_vector_type(8))) unsigned short ushort8;
typedef __attribute__((ext_vector_type(8))) short bf16x8;
typedef __attribute__((ext_vector_type(4))) float f32x4;

static __device__ __forceinline__ unsigned short f2bf(float f) {
    unsigned int u = __float_as_uint(f);
    return (unsigned short)((u + 0x7fffu + ((u >> 16) & 1u)) >> 16);
}

typedef const __attribute__((address_space(1))) unsigned int gu32;
typedef __attribute__((address_space(3))) unsigned int lu32;
static __device__ __forceinline__ void gload16(const void* g, void* l) {
    __builtin_amdgcn_global_load_lds((gu32*)g, (lu32*)l, 16, 0, 0);
}

// ---- pack x: NCHW fp32 -> zero-padded NHWC bf16 [8][98][98][192] ----
__global__ __launch_bounds__(256) void pack_x_kernel(
    const float* __restrict__ x, unsigned short* __restrict__ xp)
{
    __shared__ float tile[32][97];
    int bid = blockIdx.x;
    int ct = bid % 6; int y = (bid / 6) % NH; int n = bid / (6 * NH);
    int tid = threadIdx.x;
    int c0 = ct * 32;
    for (int i = tid; i < 32 * 96; i += 256) {
        int c = i / 96, xx = i % 96;
        tile[c][xx] = x[(((size_t)n * CIN + c0 + c) * NH + y) * NW + xx];
    }
    __syncthreads();
    for (int i = tid; i < 96 * 4; i += 256) {
        int xx = i >> 2, ch = i & 3;
        ushort8 pk;
#pragma unroll
        for (int j = 0; j < 8; ++j) pk[j] = f2bf(tile[ch * 8 + j][xx]);
        *(ushort8*)(xp + ((size_t)(n * PH + y + 1) * PH + xx + 1) * CIN + c0 + ch * 8) = pk;
    }
}

// ---- pack w: [co][ci][3][3] fp32 -> [co][(di*3+dj)*192+ci] bf16 ----
__global__ __launch_bounds__(256) void pack_w_kernel(
    const float* __restrict__ w, unsigned short* __restrict__ bw)
{
    __shared__ float ls[1728];
    int co = blockIdx.x; int tid = threadIdx.x;
    for (int i = tid; i < 1728; i += 256) ls[i] = w[(size_t)co * 1728 + i];
    __syncthreads();
    for (int i = tid; i < 1728; i += 256) {
        int sh = i / 192, ci = i % 192;
        bw[(size_t)co * 1728 + i] = f2bf(ls[ci * 9 + sh]);
    }
}

// ---- implicit-GEMM conv: M=73728, N=768, K=1728 ----
// 96x256 tile (M-tile = one (n,y) pixel row), grid 2304 = 9x256 (ZERO tail).
// BK=64, 8 waves (2Mx4N, wave 48x64). Ring-of-3 45KB LDS buffers (135KB),
// staged 2 ahead; counted per-wave vmcnt gates (waves0-3: 6 loads/tile,
// waves4-7: 5). One barrier + sched_barrier(0) per tile (rule #18).
// chunk^(row&7) swizzle, linear dst + pre-swizzled src. XCD swizzle.
#define CBUF 45056   // 12288 A + 32768 B

#define STAGE(T, BUF)                                                          \
    {                                                                          \
        int shift_ = (T) / 3, kk_ = (T) % 3;                                   \
        int aO_ = ((shift_ / 3) * PH + (shift_ % 3)) * CIN + kk_ * 64;         \
        int bO_ = (T) * 64;                                                    \
        gload16(srcA0 + aO_, smem + (BUF) + dstA0);                            \
        if (tid < 256) gload16(srcA1 + aO_, smem + (BUF) + dstA1);             \
        _Pragma("unroll")                                                      \
        for (int i_ = 0; i_ < 4; ++i_)                                         \
            gload16(srcB[i_] + bO_, smem + (BUF) + 12288 + dstB[i_]);          \
    }

#define GATE65()                                                               \
    {                                                                          \
        if (tid < 256) { asm volatile("s_waitcnt vmcnt(6)" ::: "memory"); }    \
        else           { asm volatile("s_waitcnt vmcnt(5)" ::: "memory"); }    \
    }

__global__ __launch_bounds__(512) void conv_gemm_kernel(
    const unsigned short* __restrict__ xp, const unsigned short* __restrict__ bw,
    const float* __restrict__ bias, unsigned short* __restrict__ qkq,
    unsigned short* __restrict__ vt)
{
    __shared__ __align__(16) char smem[3 * CBUF];   // 135168 B
    int bid = (blockIdx.x & 7) * 288 + (blockIdx.x >> 3);   // XCD swizzle (2304%8==0)
    int brow = (bid / 3) * 96, bcol = (bid % 3) * 256;
    int tid = threadIdx.x, lane = tid & 63;
    int wid = tid >> 6, wm = wid >> 2, wn = wid & 3;
    int g = lane >> 4;

    int nblk = brow / 9216;
    int prem = brow - nblk * 9216;
    int yy = prem / 96;   // all 96 tile rows share (nblk, yy); x = row

    // A staging: 768 slots (96 rows x 8 chunks); pass0 = all threads,
    // pass1 = tid<256 (slots 512..767)
    const unsigned short* srcA0;
    const unsigned short* srcA1;
    int dstA0, dstA1;
    {
        int r0 = tid >> 3, c0 = tid & 7;
        srcA0 = xp + ((size_t)(nblk * PH + yy) * PH + r0) * CIN
                   + ((c0 ^ (r0 & 7)) << 3);
        dstA0 = (tid & ~63) * 16;
        int s1 = 512 + tid;
        int r1 = s1 >> 3, c1 = s1 & 7;
        srcA1 = xp + ((size_t)(nblk * PH + yy) * PH + r1) * CIN
                   + ((c1 ^ (r1 & 7)) << 3);
        dstA1 = (512 + (tid & ~63)) * 16;
    }
    // B staging: 2048 slots (256 rows x 8 chunks), 4 passes
    const unsigned short* srcB[4];
    int dstB[4];
#pragma unroll
    for (int i = 0; i < 4; ++i) {
        int s = i * 512 + tid;
        int row = s >> 3, c = s & 7;
        srcB[i] = bw + (size_t)(bcol + row) * 1728 + ((c ^ (row & 7)) << 3);
        dstB[i] = (i * 512 + (tid & ~63)) * 16;
    }

    // ds_read offsets
    int arow[3], brow_[4], xof[2];
#pragma unroll
    for (int m = 0; m < 3; ++m)
        arow[m] = (wm * 48 + m * 16 + (lane & 15)) * 128;
#pragma unroll
    for (int n = 0; n < 4; ++n)
        brow_[n] = 12288 + (wn * 64 + n * 16 + (lane & 15)) * 128;
#pragma unroll
    for (int kk = 0; kk < 2; ++kk)
        xof[kk] = ((kk * 4 + g) ^ (lane & 7)) << 4;

    // prologue: stage tiles 0,1 into buffers 0,1
    STAGE(0, 0);
    STAGE(1, CBUF);

    f32x4 acc[3][4] = {};

    for (int t = 0; t < 27; ++t) {
        if (t < 26) GATE65()
        else        asm volatile("s_waitcnt vmcnt(0)" ::: "memory");
        __builtin_amdgcn_s_barrier();
        __builtin_amdgcn_sched_barrier(0);                 // rule #18
        if (t < 25) STAGE(t + 2, ((t + 2) % 3) * CBUF);
        const int cur = (t % 3) * CBUF;
        bf16x8 bf[4][2];
#pragma unroll
        for (int n = 0; n < 4; ++n)
#pragma unroll
            for (int kk = 0; kk < 2; ++kk)
                bf[n][kk] = *(const bf16x8*)(smem + cur + brow_[n] + xof[kk]);
#pragma unroll
        for (int m = 0; m < 3; ++m) {
            bf16x8 af[2];
#pragma unroll
            for (int kk = 0; kk < 2; ++kk)
                af[kk] = *(const bf16x8*)(smem + cur + arow[m] + xof[kk]);
            __builtin_amdgcn_s_setprio(1);
#pragma unroll
            for (int n = 0; n < 4; ++n)
#pragma unroll
                for (int kk = 0; kk < 2; ++kk)
                    acc[m][n] = __builtin_amdgcn_mfma_f32_16x16x32_bf16(
                        af[kk], bf[n][kk], acc[m][n], 0, 0, 0);
            __builtin_amdgcn_s_setprio(0);
        }
    }

    // ---- epilogue: sc[96][256] swizzled (48KB), then Q/K + fused V^T ----
    __syncthreads();
    unsigned short* sc = (unsigned short*)smem;
    float bn[4];
#pragma unroll
    for (int n = 0; n < 4; ++n)
        bn[n] = bias[bcol + wn * 64 + n * 16 + (lane & 15)];
#pragma unroll
    for (int m = 0; m < 3; ++m)
#pragma unroll
        for (int n = 0; n < 4; ++n) {
            int col = wn * 64 + n * 16 + (lane & 15);
            int cabs = bcol + col;
            float scale = ((cabs % 192) < 64) ? 0.125f : 1.0f;
#pragma unroll
            for (int j = 0; j < 4; ++j) {
                int row = wm * 48 + m * 16 + (lane >> 4) * 4 + j;   // 0..95
                sc[row * 256 + (col ^ ((row & 7) << 3))] =
                    f2bf((acc[m][n][j] + bn[n]) * scale);
            }
        }
    __syncthreads();
    // Q/K store: 96 rows x 32 ch-groups
#pragma unroll
    for (int i = 0; i < 6; ++i) {
        int idx = i * 512 + tid;
        int row = idx >> 5, ch = idx & 31;
        int c0 = bcol + ch * 8;
        int r192 = c0 % 192;
        if (r192 < 128) {
            ushort8 pk = *(const ushort8*)(sc + row * 256 + ((ch * 8) ^ ((row & 7) << 3)));
            *(ushort8*)(qkq + (size_t)(brow + row) * 512 + (c0 / 192) * 128 + r192) = pk;
        }
    }
    // fused V^T gather (heads whose V-range lies in this col-tile)
#pragma unroll
    for (int h = 0; h < 4; ++h) {
        int lc = h * 192 + 128 - bcol;
        if (lc < 0 || lc > 192) continue;
        unsigned short* vth = vt + (size_t)h * 4718592;  // 8*64*9216
#pragma unroll
        for (int it = 0; it < 2; ++it) {
            int i = it * 512 + tid;
            if (i < 768) {
                int d = i & 63, pxb = i >> 6;        // pxb 0..11
                ushort8 pk;
#pragma unroll
                for (int j = 0; j < 8; ++j) {
                    int px = pxb * 8 + j;            // 0..95
                    pk[j] = sc[px * 256 + ((lc + d) ^ ((px & 7) << 3))];
                }
                *(ushort8*)(vth + ((size_t)(nblk * 64 + d)) * 9216
                            + prem + pxb * 8) = pk;
            }
        }
    }
}

// ---- MFMA neighborhood attention, single pass, 3-ROW blocks ---- (r22 verified)
#define SLAB 24576
template<int KS>
static __device__ __forceinline__ void na_body(
    const unsigned short* __restrict__ qkq, const unsigned short* __restrict__ vt,
    float* __restrict__ out, int head, int bid, char* nsm)
{
    constexpr int PAD = KS / 2;
    int yp = bid % 32, n = bid / 32;
    int y0 = yp * 3;
    int tid = threadIdx.x;
    int wv = tid >> 6, lane = tid & 63;
    int g = lane >> 4, pix = lane & 15;
    int x0 = wv * 16;
    int x = x0 + pix;
    int W = x0 - 8;

    size_t qb0 = ((size_t)((n * 96 + y0) * 96 + x)) * 512 + (size_t)head * 128;
    bf16x8 qa0 = *(const bf16x8*)(qkq + qb0 + g * 8);
    bf16x8 qa1 = *(const bf16x8*)(qkq + qb0 + 32 + g * 8);
    bf16x8 qc0 = *(const bf16x8*)(qkq + qb0 + 96 * 512 + g * 8);
    bf16x8 qc1 = *(const bf16x8*)(qkq + qb0 + 96 * 512 + 32 + g * 8);
    bf16x8 qe0 = *(const bf16x8*)(qkq + qb0 + 2 * 96 * 512 + g * 8);
    bf16x8 qe1 = *(const bf16x8*)(qkq + qb0 + 2 * 96 * 512 + 32 + g * 8);
    asm volatile("s_waitcnt vmcnt(0)" ::: "memory");  // drain Q: vmcnt counts staging only

    const size_t hoff = (size_t)head * 128 + 64;
#define STAGEKV(DI, BUF)                                                       \
    {                                                                          \
        int iy_ = min(max(y0 + (DI) - PAD, 0), 95);                            \
        size_t rb_ = ((size_t)((n * 96 + iy_) * 96)) * 512 + hoff;             \
        _Pragma("unroll")                                                      \
        for (int i_ = 0; i_ < 2; ++i_) {                                       \
            int ch_ = i_ * 384 + tid;                                          \
            int xx_ = ch_ >> 3, c8_ = (ch_ & 7) ^ (xx_ & 7);                   \
            gload16(qkq + rb_ + (size_t)xx_ * 512 + c8_ * 8,                   \
                    nsm + (BUF) * SLAB + (i_ * 384 + (tid & ~63)) * 16);       \
        }                                                                      \
        _Pragma("unroll")                                                      \
        for (int i_ = 0; i_ < 2; ++i_) {                                       \
            int ch_ = i_ * 384 + tid;                                          \
            int d_ = ch_ / 12, c_ = ch_ % 12;                                  \
            int cs_ = c_ ^ ((d_ >> 1) & 3);                                    \
            gload16(vt + (((size_t)(n * 64 + d_) * 96 + iy_)) * 96 + cs_ * 8,  \
                    nsm + (BUF) * SLAB + 12288 + (i_ * 384 + (tid & ~63)) * 16); \
        }                                                                      \
    }

    STAGEKV(0, 0);
    STAGEKV(1, 1);

    float l0 = 0.f, l1 = 0.f, l2 = 0.f;
    f32x4 O0[4] = {}, O1[4] = {}, O2[4] = {};
    int addrA = ((2 * (g & 1)) * 16 + pix) * 4;
    int addrB = addrA + 64;
    bool kthi = (g >> 1) != 0;
    int cxg = min(max(2 * wv - 1 + g, 0), 11);
    int vbase = 12288 + pix * 192 + ((cxg ^ ((pix >> 1) & 3)) << 4);

#define ROWCOMP(QF0, QF1, L, O)                                                \
    {                                                                          \
        unsigned int w0[2], w1[2];                                             \
        _Pragma("unroll")                                                      \
        for (int kt = 0; kt < 2; ++kt) {                                       \
            f32x4 tt = {};                                                     \
            tt = __builtin_amdgcn_mfma_f32_16x16x32_bf16(kf0[kt], QF0, tt, 0, 0, 0); \
            tt = __builtin_amdgcn_mfma_f32_16x16x32_bf16(kf1[kt], QF1, tt, 0, 0, 0); \
            float p[4];                                                        \
            _Pragma("unroll")                                                  \
            for (int r = 0; r < 4; ++r) {                                      \
                int kix = W + kt * 16 + g * 4 + r;                             \
                bool valid = ((unsigned)(kix - x + PAD) <= (unsigned)(2 * PAD)) && \
                             ((unsigned)kix < 96u);                            \
                p[r] = valid ? __expf(tt[r]) : 0.f;                            \
            }                                                                  \
            L += (p[0] + p[1]) + (p[2] + p[3]);                                \
            asm("v_cvt_pk_bf16_f32 %0, %1, %2" : "=v"(w0[kt]) : "v"(p[0]), "v"(p[1])); \
            asm("v_cvt_pk_bf16_f32 %0, %1, %2" : "=v"(w1[kt]) : "v"(p[2]), "v"(p[3])); \
        }                                                                      \
        int a0 = __builtin_amdgcn_ds_bpermute(addrA, (int)w0[0]);              \
        int b0 = __builtin_amdgcn_ds_bpermute(addrA, (int)w0[1]);              \
        int a1 = __builtin_amdgcn_ds_bpermute(addrA, (int)w1[0]);              \
        int b1 = __builtin_amdgcn_ds_bpermute(addrA, (int)w1[1]);              \
        int a2 = __builtin_amdgcn_ds_bpermute(addrB, (int)w0[0]);              \
        int b2 = __builtin_amdgcn_ds_bpermute(addrB, (int)w0[1]);              \
        int a3 = __builtin_amdgcn_ds_bpermute(addrB, (int)w1[0]);              \
        int b3 = __builtin_amdgcn_ds_bpermute(addrB, (int)w1[1]);              \
        union { int u[4]; bf16x8 v; } pa;                                      \
        pa.u[0] = kthi ? b0 : a0;                                              \
        pa.u[1] = kthi ? b1 : a1;                                              \
        pa.u[2] = kthi ? b2 : a2;                                              \
        pa.u[3] = kthi ? b3 : a3;                                              \
        _Pragma("unroll")                                                      \
        for (int dc = 0; dc < 4; ++dc)                                         \
            O[dc] = __builtin_amdgcn_mfma_f32_16x16x32_bf16(pa.v, vf[dc], O[dc], 0, 0, 0); \
    }

#pragma unroll
    for (int di = 0; di <= KS + 1; ++di) {
        if (di <= KS) asm volatile("s_waitcnt vmcnt(4)" ::: "memory");
        else          asm volatile("s_waitcnt vmcnt(0)" ::: "memory");
        __builtin_amdgcn_s_barrier();
        __builtin_amdgcn_sched_barrier(0);
        if (di + 2 <= KS + 1) STAGEKV(di + 2, (di + 2) % 3);
        int iy = y0 + di - PAD;
        if (iy < 0 || iy >= 96) continue;     // block-uniform skip (all rows)
        const char* kb = nsm + (di % 3) * SLAB;

        bf16x8 kf0[2], kf1[2];
#pragma unroll
        for (int kt = 0; kt < 2; ++kt) {
            int kix_l = W + kt * 16 + pix;
            int ixc = min(max(kix_l, 0), 95);
            const char* kr = kb + ixc * 128;
            kf0[kt] = *(const bf16x8*)(kr + ((g ^ (ixc & 7)) << 4));
            kf1[kt] = *(const bf16x8*)(kr + (((4 + g) ^ (ixc & 7)) << 4));
        }
        bf16x8 vf[4];
#pragma unroll
        for (int dc = 0; dc < 4; ++dc)
            vf[dc] = *(const bf16x8*)(kb + dc * 3072 + vbase);

        if (di < KS)              ROWCOMP(qa0, qa1, l0, O0);  // row y0:   tap di
        if (di >= 1 && di <= KS)  ROWCOMP(qc0, qc1, l1, O1);  // row y0+1: tap di-1
        if (di >= 2)              ROWCOMP(qe0, qe1, l2, O2);  // row y0+2: tap di-2
    }

    l0 += __shfl_xor(l0, 16, 64); l0 += __shfl_xor(l0, 32, 64);
    l1 += __shfl_xor(l1, 16, 64); l1 += __shfl_xor(l1, 32, 64);
    l2 += __shfl_xor(l2, 16, 64); l2 += __shfl_xor(l2, 32, 64);
    float li0 = 1.0f / l0, li1 = 1.0f / l1, li2 = 1.0f / l2;
    float lj0[4], lj1[4], lj2[4];
#pragma unroll
    for (int j = 0; j < 4; ++j) {
        lj0[j] = __uint_as_float((unsigned)__builtin_amdgcn_ds_bpermute(
            (4 * g + j) * 4, (int)__float_as_uint(li0)));
        lj1[j] = __uint_as_float((unsigned)__builtin_amdgcn_ds_bpermute(
            (4 * g + j) * 4, (int)__float_as_uint(li1)));
        lj2[j] = __uint_as_float((unsigned)__builtin_amdgcn_ds_bpermute(
            (4 * g + j) * 4, (int)__float_as_uint(li2)));
    }
    __syncthreads();   // full fence: ring dead before sO (aliased) is written
    float (*sO3)[64][97] = (float(*)[64][97])nsm;   // 3 planes, 74.5KB
#pragma unroll
    for (int dc = 0; dc < 4; ++dc)
#pragma unroll
        for (int j = 0; j < 4; ++j) {
            sO3[0][dc * 16 + pix][x0 + g * 4 + j] = O0[dc][j] * lj0[j];
            sO3[1][dc * 16 + pix][x0 + g * 4 + j] = O1[dc][j] * lj1[j];
            sO3[2][dc * 16 + pix][x0 + g * 4 + j] = O2[dc][j] * lj2[j];
        }
    __syncthreads();
    for (int i = tid; i < 4608; i += 384) {
        int r = i / 1536;
        int rem = i - r * 1536;
        int d = rem / 24, xq = rem % 24;
        float4 v4 = { sO3[r][d][xq * 4], sO3[r][d][xq * 4 + 1],
                      sO3[r][d][xq * 4 + 2], sO3[r][d][xq * 4 + 3] };
        *(float4*)(out + ((size_t)(head * 8 + n) * 64 + d) * 9216
                   + (y0 + r) * 96 + xq * 4) = v4;
    }
}

// all 4 heads interleaved: head = blockIdx.x & 3 (tail-balanced)
__global__ __launch_bounds__(384, 2) void na_mfma_all(
    const unsigned short* __restrict__ qkq, const unsigned short* __restrict__ vt,
    float* __restrict__ out)
{
    __shared__ __align__(16) char nsm[74496];   // ring 73.7KB; sO3 74.5KB
    int head = blockIdx.x & 3;
    int bid = blockIdx.x >> 2;                  // yp = bid%32, n = bid/32
    switch (head) {
        case 0: na_body<3>(qkq, vt,               out, 0, bid, nsm); break;
        case 1: na_body<5>(qkq, vt + 4718592,     out, 1, bid, nsm); break;
        case 2: na_body<7>(qkq, vt + 2 * 4718592, out, 2, bid, nsm); break;
        default: na_body<9>(qkq, vt + 3 * 4718592, out, 3, bid, nsm); break;
    }
}

extern "C" void kernel_launch(void* const* d_in, const int* in_sizes, int n_in,
                              void* d_out, int out_size, void* d_ws, size_t ws_size,
                              hipStream_t stream) {
    const float* x  = (const float*)d_in[0];
    const float* w  = (const float*)d_in[1];
    const float* b  = (const float*)d_in[2];
    float* out = (float*)d_out;

    unsigned short* qkq  = (unsigned short*)d_ws;                       // 75497472 B
    unsigned short* vt   = (unsigned short*)((char*)d_ws + 75497472);   // 37748736 B
    unsigned short* xpad = (unsigned short*)((char*)d_ws + 113246208);  // 29503488 B
    unsigned short* bw   = (unsigned short*)((char*)d_ws + 142749696);  // 2654208 B

    hipMemsetAsync(xpad, 0, 29503488, stream);
    pack_x_kernel<<<NB * NH * 6, 256, 0, stream>>>(x, xpad);
    pack_w_kernel<<<COUT, 256, 0, stream>>>(w, bw);
    conv_gemm_kernel<<<2304, 512, 0, stream>>>(xpad, bw, b, qkq, vt);

    na_mfma_all<<<4 * 256, 384, 0, stream>>>(qkq, vt, out);
}

// Round 24
// 312.951 us; speedup vs baseline: 1.0906x; 1.0906x over previous
//
#include <hip/hip_runtime.h>
#include <hip/hip_bf16.h>

#define NH 96
#define NW 96
#define NB 8
#define CIN 192
#define COUT 768   // 4 heads * 3 * 64
#define PH 98      // padded spatial dim

typedef __attribute__((ext_vector_type(8))) unsigned short ushort8;
typedef __attribute__((ext_vector_type(8))) short bf16x8;
typedef __attribute__((ext_vector_type(4))) float f32x4;

static __device__ __forceinline__ unsigned short f2bf(float f) {
    unsigned int u = __float_as_uint(f);
    return (unsigned short)((u + 0x7fffu + ((u >> 16) & 1u)) >> 16);
}

typedef const __attribute__((address_space(1))) unsigned int gu32;
typedef __attribute__((address_space(3))) unsigned int lu32;
static __device__ __forceinline__ void gload16(const void* g, void* l) {
    __builtin_amdgcn_global_load_lds((gu32*)g, (lu32*)l, 16, 0, 0);
}

// ---- zero only the 1.2MB halo of xpad (rows 0/97, cols 0/97 per image) ----
__global__ __launch_bounds__(256) void zero_halo_kernel(unsigned short* __restrict__ xp)
{
    int idx = blockIdx.x * 256 + threadIdx.x;   // 0 .. 74495
    int n = idx / 9312, cid = idx - n * 9312;
    size_t base = (size_t)n * PH * PH * CIN;
    size_t off;
    if (cid < 2352) {                       // row y=0
        off = base + (size_t)cid * 8;
    } else if (cid < 4704) {                // row y=97
        off = base + (size_t)97 * PH * CIN + (size_t)(cid - 2352) * 8;
    } else {                                // cols x=0 / x=97, y=1..96
        int e = cid - 4704;
        int y = e / 48 + 1;
        int s = (e % 48) / 24;
        int cc = e % 24;
        off = base + ((size_t)y * PH + (s ? 97 : 0)) * CIN + cc * 8;
    }
    ushort8 z = {};
    *(ushort8*)(xp + off) = z;
}

// ---- pack x: NCHW fp32 -> zero-padded NHWC bf16 [8][98][98][192] ----
__global__ __launch_bounds__(256) void pack_x_kernel(
    const float* __restrict__ x, unsigned short* __restrict__ xp)
{
    __shared__ float tile[32][97];
    int bid = blockIdx.x;
    int ct = bid % 6; int y = (bid / 6) % NH; int n = bid / (6 * NH);
    int tid = threadIdx.x;
    int c0 = ct * 32;
    for (int i = tid; i < 32 * 96; i += 256) {
        int c = i / 96, xx = i % 96;
        tile[c][xx] = x[(((size_t)n * CIN + c0 + c) * NH + y) * NW + xx];
    }
    __syncthreads();
    for (int i = tid; i < 96 * 4; i += 256) {
        int xx = i >> 2, ch = i & 3;
        ushort8 pk;
#pragma unroll
        for (int j = 0; j < 8; ++j) pk[j] = f2bf(tile[ch * 8 + j][xx]);
        *(ushort8*)(xp + ((size_t)(n * PH + y + 1) * PH + xx + 1) * CIN + c0 + ch * 8) = pk;
    }
}

// ---- pack w: [co][ci][3][3] fp32 -> [co][(di*3+dj)*192+ci] bf16 ----
__global__ __launch_bounds__(256) void pack_w_kernel(
    const float* __restrict__ w, unsigned short* __restrict__ bw)
{
    __shared__ float ls[1728];
    int co = blockIdx.x; int tid = threadIdx.x;
    for (int i = tid; i < 1728; i += 256) ls[i] = w[(size_t)co * 1728 + i];
    __syncthreads();
    for (int i = tid; i < 1728; i += 256) {
        int sh = i / 192, ci = i % 192;
        bw[(size_t)co * 1728 + i] = f2bf(ls[ci * 9 + sh]);
    }
}

// ---- implicit-GEMM conv (r20-verified best): 256x256 tile, BK=64, 8 waves,
// 2x64KB LDS dbuf, ONE vmcnt(0)+barrier per K-tile, 4 phases
// {stage quarter of t+1 || ds_read 4 A-frags || 16 MFMA}, no intra-tile
// barriers. chunk^(row&7) swizzle, linear LDS dst + pre-swizzled src.
__global__ __launch_bounds__(512) void conv_gemm_kernel(
    const unsigned short* __restrict__ xp, const unsigned short* __restrict__ bw,
    const float* __restrict__ bias, unsigned short* __restrict__ qkq,
    unsigned short* __restrict__ vt)
{
    __shared__ __align__(16) char smem[131072];   // 2 x (32KB A + 32KB B)
    int bid = (blockIdx.x & 7) * 108 + (blockIdx.x >> 3);   // XCD swizzle (864%8==0)
    int brow = (bid / 3) * 256, bcol = (bid % 3) * 256;
    int tid = threadIdx.x, lane = tid & 63;
    int wid = tid >> 6, wm = wid >> 2, wn = wid & 3;
    int g = lane >> 4;

    const unsigned short* srcA[2][2];
    const unsigned short* srcB[2][2];
#pragma unroll
    for (int h = 0; h < 2; ++h)
#pragma unroll
        for (int i = 0; i < 2; ++i) {
            int s = i * 512 + tid;
            int rl = s >> 3, c = s & 7;          // 128 rows x 8 chunks of 16B
            int csw = (c ^ (rl & 7)) << 3;       // pre-swizzled source chunk
            int p = brow + h * 128 + rl;
            int n = p / 9216; int rem = p - n * 9216;
            int y = rem / 96; int xx = rem - y * 96;
            srcA[h][i] = xp + ((size_t)(n * PH + y) * PH + xx) * CIN + csw;
            srcB[h][i] = bw + (size_t)(bcol + h * 128 + rl) * 1728 + csw;
        }
    int dsto[2];
#pragma unroll
    for (int i = 0; i < 2; ++i) dsto[i] = (i * 512 + (tid & ~63)) * 16;

#define STAGEU(T, U, BUF)                                                      \
    {                                                                          \
        int shift_ = (T) / 3, kk_ = (T) % 3;                                   \
        if ((U) < 2) {                                                         \
            int aO_ = ((shift_ / 3) * PH + (shift_ % 3)) * CIN + kk_ * 64;     \
            _Pragma("unroll")                                                  \
            for (int i_ = 0; i_ < 2; ++i_)                                     \
                gload16(srcA[(U)][i_] + aO_,                                   \
                        smem + (BUF) + (U) * 16384 + dsto[i_]);                \
        } else {                                                               \
            int bO_ = (T) * 64;                                                \
            _Pragma("unroll")                                                  \
            for (int i_ = 0; i_ < 2; ++i_)                                     \
                gload16(srcB[(U) - 2][i_] + bO_,                               \
                        smem + (BUF) + 32768 + ((U) - 2) * 16384 + dsto[i_]);  \
        }                                                                      \
    }

    int arow[8], brow_[4], xof[2];
#pragma unroll
    for (int m = 0; m < 8; ++m)
        arow[m] = (wm * 128 + m * 16 + (lane & 15)) * 128;
#pragma unroll
    for (int n = 0; n < 4; ++n)
        brow_[n] = 32768 + (wn * 64 + n * 16 + (lane & 15)) * 128;
#pragma unroll
    for (int kk = 0; kk < 2; ++kk)
        xof[kk] = ((kk * 4 + g) ^ (lane & 7)) << 4;

    STAGEU(0, 0, 0); STAGEU(0, 1, 0); STAGEU(0, 2, 0); STAGEU(0, 3, 0);

    f32x4 acc[8][4] = {};

    for (int t = 0; t < 27; ++t) {
        asm volatile("s_waitcnt vmcnt(0)" ::: "memory");   // tile t fully landed
        __builtin_amdgcn_s_barrier();
        __builtin_amdgcn_sched_barrier(0);                 // rule #18
        const int cur = (t & 1) << 16;
        const int nxt = cur ^ 65536;
        bf16x8 bf[4][2];
#pragma unroll
        for (int n = 0; n < 4; ++n)
#pragma unroll
            for (int kk = 0; kk < 2; ++kk)
                bf[n][kk] = *(const bf16x8*)(smem + cur + brow_[n] + xof[kk]);
#pragma unroll
        for (int p = 0; p < 4; ++p) {
            if (t < 26) STAGEU(t + 1, p, nxt);
            bf16x8 af[2][2];
#pragma unroll
            for (int mm = 0; mm < 2; ++mm)
#pragma unroll
                for (int kk = 0; kk < 2; ++kk)
                    af[mm][kk] = *(const bf16x8*)(smem + cur + arow[2 * p + mm] + xof[kk]);
            __builtin_amdgcn_s_setprio(1);
#pragma unroll
            for (int mm = 0; mm < 2; ++mm)
#pragma unroll
                for (int n = 0; n < 4; ++n)
#pragma unroll
                    for (int kk = 0; kk < 2; ++kk)
                        acc[2 * p + mm][n] = __builtin_amdgcn_mfma_f32_16x16x32_bf16(
                            af[mm][kk], bf[n][kk], acc[2 * p + mm][n], 0, 0, 0);
            __builtin_amdgcn_s_setprio(0);
        }
    }

    // ---- epilogue: sc[row][col^((row&7)<<3)] stride 256, 128KB ----
    __syncthreads();
    unsigned short* sc = (unsigned short*)smem;
    float bn[4];
#pragma unroll
    for (int n = 0; n < 4; ++n)
        bn[n] = bias[bcol + wn * 64 + n * 16 + (lane & 15)];
#pragma unroll
    for (int m = 0; m < 8; ++m)
#pragma unroll
        for (int n = 0; n < 4; ++n) {
            int col = wn * 64 + n * 16 + (lane & 15);
            int cabs = bcol + col;
            float scale = ((cabs % 192) < 64) ? 0.125f : 1.0f;
#pragma unroll
            for (int j = 0; j < 4; ++j) {
                int row = wm * 128 + m * 16 + (lane >> 4) * 4 + j;
                sc[row * 256 + (col ^ ((row & 7) << 3))] =
                    f2bf((acc[m][n][j] + bn[n]) * scale);
            }
        }
    __syncthreads();
#pragma unroll
    for (int i = 0; i < 16; ++i) {
        int idx = i * 512 + tid;
        int row = idx >> 5, ch = idx & 31;
        int c0 = bcol + ch * 8;
        int r192 = c0 % 192;
        if (r192 < 128) {
            ushort8 pk = *(const ushort8*)(sc + row * 256 + ((ch * 8) ^ ((row & 7) << 3)));
            *(ushort8*)(qkq + (size_t)(brow + row) * 512 + (c0 / 192) * 128 + r192) = pk;
        }
    }
    int nblk = brow / 9216;
    int prem = brow - nblk * 9216;
#pragma unroll
    for (int h = 0; h < 4; ++h) {
        int lc = h * 192 + 128 - bcol;
        if (lc < 0 || lc > 192) continue;
        unsigned short* vth = vt + (size_t)h * 4718592;  // 8*64*9216
#pragma unroll
        for (int it = 0; it < 4; ++it) {
            int i = it * 512 + tid;
            int d = i & 63, pxb = i >> 6;
            ushort8 pk;
#pragma unroll
            for (int j = 0; j < 8; ++j) {
                int px = pxb * 8 + j;
                pk[j] = sc[px * 256 + ((lc + d) ^ ((px & 7) << 3))];
            }
            *(ushort8*)(vth + ((size_t)(nblk * 64 + d)) * 9216 + prem + pxb * 8) = pk;
        }
    }
}

// ---- MFMA neighborhood attention, single pass, 3-ROW blocks ---- (r22 verified)
#define SLAB 24576
template<int KS>
static __device__ __forceinline__ void na_body(
    const unsigned short* __restrict__ qkq, const unsigned short* __restrict__ vt,
    float* __restrict__ out, int head, int bid, char* nsm)
{
    constexpr int PAD = KS / 2;
    int yp = bid % 32, n = bid / 32;
    int y0 = yp * 3;
    int tid = threadIdx.x;
    int wv = tid >> 6, lane = tid & 63;
    int g = lane >> 4, pix = lane & 15;
    int x0 = wv * 16;
    int x = x0 + pix;
    int W = x0 - 8;

    size_t qb0 = ((size_t)((n * 96 + y0) * 96 + x)) * 512 + (size_t)head * 128;
    bf16x8 qa0 = *(const bf16x8*)(qkq + qb0 + g * 8);
    bf16x8 qa1 = *(const bf16x8*)(qkq + qb0 + 32 + g * 8);
    bf16x8 qc0 = *(const bf16x8*)(qkq + qb0 + 96 * 512 + g * 8);
    bf16x8 qc1 = *(const bf16x8*)(qkq + qb0 + 96 * 512 + 32 + g * 8);
    bf16x8 qe0 = *(const bf16x8*)(qkq + qb0 + 2 * 96 * 512 + g * 8);
    bf16x8 qe1 = *(const bf16x8*)(qkq + qb0 + 2 * 96 * 512 + 32 + g * 8);
    asm volatile("s_waitcnt vmcnt(0)" ::: "memory");  // drain Q: vmcnt counts staging only

    const size_t hoff = (size_t)head * 128 + 64;
#define STAGEKV(DI, BUF)                                                       \
    {                                                                          \
        int iy_ = min(max(y0 + (DI) - PAD, 0), 95);                            \
        size_t rb_ = ((size_t)((n * 96 + iy_) * 96)) * 512 + hoff;             \
        _Pragma("unroll")                                                      \
        for (int i_ = 0; i_ < 2; ++i_) {                                       \
            int ch_ = i_ * 384 + tid;                                          \
            int xx_ = ch_ >> 3, c8_ = (ch_ & 7) ^ (xx_ & 7);                   \
            gload16(qkq + rb_ + (size_t)xx_ * 512 + c8_ * 8,                   \
                    nsm + (BUF) * SLAB + (i_ * 384 + (tid & ~63)) * 16);       \
        }                                                                      \
        _Pragma("unroll")                                                      \
        for (int i_ = 0; i_ < 2; ++i_) {                                       \
            int ch_ = i_ * 384 + tid;                                          \
            int d_ = ch_ / 12, c_ = ch_ % 12;                                  \
            int cs_ = c_ ^ ((d_ >> 1) & 3);                                    \
            gload16(vt + (((size_t)(n * 64 + d_) * 96 + iy_)) * 96 + cs_ * 8,  \
                    nsm + (BUF) * SLAB + 12288 + (i_ * 384 + (tid & ~63)) * 16); \
        }                                                                      \
    }

    STAGEKV(0, 0);
    STAGEKV(1, 1);

    float l0 = 0.f, l1 = 0.f, l2 = 0.f;
    f32x4 O0[4] = {}, O1[4] = {}, O2[4] = {};
    int addrA = ((2 * (g & 1)) * 16 + pix) * 4;
    int addrB = addrA + 64;
    bool kthi = (g >> 1) != 0;
    int cxg = min(max(2 * wv - 1 + g, 0), 11);
    int vbase = 12288 + pix * 192 + ((cxg ^ ((pix >> 1) & 3)) << 4);

#define ROWCOMP(QF0, QF1, L, O)                                                \
    {                                                                          \
        unsigned int w0[2], w1[2];                                             \
        _Pragma("unroll")                                                      \
        for (int kt = 0; kt < 2; ++kt) {                                       \
            f32x4 tt = {};                                                     \
            tt = __builtin_amdgcn_mfma_f32_16x16x32_bf16(kf0[kt], QF0, tt, 0, 0, 0); \
            tt = __builtin_amdgcn_mfma_f32_16x16x32_bf16(kf1[kt], QF1, tt, 0, 0, 0); \
            float p[4];                                                        \
            _Pragma("unroll")                                                  \
            for (int r = 0; r < 4; ++r) {                                      \
                int kix = W + kt * 16 + g * 4 + r;                             \
                bool valid = ((unsigned)(kix - x + PAD) <= (unsigned)(2 * PAD)) && \
                             ((unsigned)kix < 96u);                            \
                p[r] = valid ? __expf(tt[r]) : 0.f;                            \
            }                                                                  \
            L += (p[0] + p[1]) + (p[2] + p[3]);                                \
            asm("v_cvt_pk_bf16_f32 %0, %1, %2" : "=v"(w0[kt]) : "v"(p[0]), "v"(p[1])); \
            asm("v_cvt_pk_bf16_f32 %0, %1, %2" : "=v"(w1[kt]) : "v"(p[2]), "v"(p[3])); \
        }                                                                      \
        int a0 = __builtin_amdgcn_ds_bpermute(addrA, (int)w0[0]);              \
        int b0 = __builtin_amdgcn_ds_bpermute(addrA, (int)w0[1]);              \
        int a1 = __builtin_amdgcn_ds_bpermute(addrA, (int)w1[0]);              \
        int b1 = __builtin_amdgcn_ds_bpermute(addrA, (int)w1[1]);              \
        int a2 = __builtin_amdgcn_ds_bpermute(addrB, (int)w0[0]);              \
        int b2 = __builtin_amdgcn_ds_bpermute(addrB, (int)w0[1]);              \
        int a3 = __builtin_amdgcn_ds_bpermute(addrB, (int)w1[0]);              \
        int b3 = __builtin_amdgcn_ds_bpermute(addrB, (int)w1[1]);              \
        union { int u[4]; bf16x8 v; } pa;                                      \
        pa.u[0] = kthi ? b0 : a0;                                              \
        pa.u[1] = kthi ? b1 : a1;                                              \
        pa.u[2] = kthi ? b2 : a2;                                              \
        pa.u[3] = kthi ? b3 : a3;                                              \
        _Pragma("unroll")                                                      \
        for (int dc = 0; dc < 4; ++dc)                                         \
            O[dc] = __builtin_amdgcn_mfma_f32_16x16x32_bf16(pa.v, vf[dc], O[dc], 0, 0, 0); \
    }

#pragma unroll
    for (int di = 0; di <= KS + 1; ++di) {
        if (di <= KS) asm volatile("s_waitcnt vmcnt(4)" ::: "memory");
        else          asm volatile("s_waitcnt vmcnt(0)" ::: "memory");
        __builtin_amdgcn_s_barrier();
        __builtin_amdgcn_sched_barrier(0);
        if (di + 2 <= KS + 1) STAGEKV(di + 2, (di + 2) % 3);
        int iy = y0 + di - PAD;
        if (iy < 0 || iy >= 96) continue;     // block-uniform skip (all rows)
        const char* kb = nsm + (di % 3) * SLAB;

        bf16x8 kf0[2], kf1[2];
#pragma unroll
        for (int kt = 0; kt < 2; ++kt) {
            int kix_l = W + kt * 16 + pix;
            int ixc = min(max(kix_l, 0), 95);
            const char* kr = kb + ixc * 128;
            kf0[kt] = *(const bf16x8*)(kr + ((g ^ (ixc & 7)) << 4));
            kf1[kt] = *(const bf16x8*)(kr + (((4 + g) ^ (ixc & 7)) << 4));
        }
        bf16x8 vf[4];
#pragma unroll
        for (int dc = 0; dc < 4; ++dc)
            vf[dc] = *(const bf16x8*)(kb + dc * 3072 + vbase);

        if (di < KS)              ROWCOMP(qa0, qa1, l0, O0);  // row y0:   tap di
        if (di >= 1 && di <= KS)  ROWCOMP(qc0, qc1, l1, O1);  // row y0+1: tap di-1
        if (di >= 2)              ROWCOMP(qe0, qe1, l2, O2);  // row y0+2: tap di-2
    }

    l0 += __shfl_xor(l0, 16, 64); l0 += __shfl_xor(l0, 32, 64);
    l1 += __shfl_xor(l1, 16, 64); l1 += __shfl_xor(l1, 32, 64);
    l2 += __shfl_xor(l2, 16, 64); l2 += __shfl_xor(l2, 32, 64);
    float li0 = 1.0f / l0, li1 = 1.0f / l1, li2 = 1.0f / l2;
    float lj0[4], lj1[4], lj2[4];
#pragma unroll
    for (int j = 0; j < 4; ++j) {
        lj0[j] = __uint_as_float((unsigned)__builtin_amdgcn_ds_bpermute(
            (4 * g + j) * 4, (int)__float_as_uint(li0)));
        lj1[j] = __uint_as_float((unsigned)__builtin_amdgcn_ds_bpermute(
            (4 * g + j) * 4, (int)__float_as_uint(li1)));
        lj2[j] = __uint_as_float((unsigned)__builtin_amdgcn_ds_bpermute(
            (4 * g + j) * 4, (int)__float_as_uint(li2)));
    }
    __syncthreads();   // full fence: ring dead before sO (aliased) is written
    float (*sO3)[64][97] = (float(*)[64][97])nsm;   // 3 planes, 74.5KB
#pragma unroll
    for (int dc = 0; dc < 4; ++dc)
#pragma unroll
        for (int j = 0; j < 4; ++j) {
            sO3[0][dc * 16 + pix][x0 + g * 4 + j] = O0[dc][j] * lj0[j];
            sO3[1][dc * 16 + pix][x0 + g * 4 + j] = O1[dc][j] * lj1[j];
            sO3[2][dc * 16 + pix][x0 + g * 4 + j] = O2[dc][j] * lj2[j];
        }
    __syncthreads();
    for (int i = tid; i < 4608; i += 384) {
        int r = i / 1536;
        int rem = i - r * 1536;
        int d = rem / 24, xq = rem % 24;
        float4 v4 = { sO3[r][d][xq * 4], sO3[r][d][xq * 4 + 1],
                      sO3[r][d][xq * 4 + 2], sO3[r][d][xq * 4 + 3] };
        *(float4*)(out + ((size_t)(head * 8 + n) * 64 + d) * 9216
                   + (y0 + r) * 96 + xq * 4) = v4;
    }
}

// all 4 heads interleaved: head = blockIdx.x & 3 (tail-balanced)
__global__ __launch_bounds__(384, 2) void na_mfma_all(
    const unsigned short* __restrict__ qkq, const unsigned short* __restrict__ vt,
    float* __restrict__ out)
{
    __shared__ __align__(16) char nsm[74496];   // ring 73.7KB; sO3 74.5KB
    int head = blockIdx.x & 3;
    int bid = blockIdx.x >> 2;                  // yp = bid%32, n = bid/32
    switch (head) {
        case 0: na_body<3>(qkq, vt,               out, 0, bid, nsm); break;
        case 1: na_body<5>(qkq, vt + 4718592,     out, 1, bid, nsm); break;
        case 2: na_body<7>(qkq, vt + 2 * 4718592, out, 2, bid, nsm); break;
        default: na_body<9>(qkq, vt + 3 * 4718592, out, 3, bid, nsm); break;
    }
}

extern "C" void kernel_launch(void* const* d_in, const int* in_sizes, int n_in,
                              void* d_out, int out_size, void* d_ws, size_t ws_size,
                              hipStream_t stream) {
    const float* x  = (const float*)d_in[0];
    const float* w  = (const float*)d_in[1];
    const float* b  = (const float*)d_in[2];
    float* out = (float*)d_out;

    unsigned short* qkq  = (unsigned short*)d_ws;                       // 75497472 B
    unsigned short* vt   = (unsigned short*)((char*)d_ws + 75497472);   // 37748736 B
    unsigned short* xpad = (unsigned short*)((char*)d_ws + 113246208);  // 29503488 B
    unsigned short* bw   = (unsigned short*)((char*)d_ws + 142749696);  // 2654208 B

    zero_halo_kernel<<<291, 256, 0, stream>>>(xpad);
    pack_x_kernel<<<NB * NH * 6, 256, 0, stream>>>(x, xpad);
    pack_w_kernel<<<COUT, 256, 0, stream>>>(w, bw);
    conv_gemm_kernel<<<864, 512, 0, stream>>>(xpad, bw, b, qkq, vt);

    na_mfma_all<<<4 * 256, 384, 0, stream>>>(qkq, vt, out);
}